// Round 13
// baseline (342.342 us; speedup 1.0000x reference)
//
#include <hip/hip_runtime.h>

typedef __attribute__((ext_vector_type(8))) short short8;
typedef __attribute__((ext_vector_type(16))) float f32x16;

#define MFMA32 __builtin_amdgcn_mfma_f32_32x32x16_bf16

__device__ __forceinline__ unsigned short f2bf(float f) {
  unsigned int u = __float_as_uint(f);
  u += 0x7fffu + ((u >> 16) & 1u);
  return (unsigned short)(u >> 16);
}

// Pre-pack the 6 weight matrices fp32 [k][n] -> bf16 MFMA-fragment order:
// wt[(((s*6 + g)*8 + c)*64 + l)*8 + j] = G_g[k][n]
//   with k = s*16 + (l>>5)*8 + j, n = c*32 + (l&31)
// One (slab,gate,chunk) brick = 1 KB = one wave's B-fragment, contiguous.
__global__ __launch_bounds__(256) void wprep(
    const float* __restrict__ Wu, const float* __restrict__ Wr, const float* __restrict__ Wh,
    const float* __restrict__ Uu, const float* __restrict__ Ur, const float* __restrict__ Uh,
    unsigned short* __restrict__ wt) {
  int idx = blockIdx.x * 256 + threadIdx.x;   // 0 .. 6*65536-1
  int j = idx & 7;
  int l = (idx >> 3) & 63;
  int c = (idx >> 9) & 7;
  int sg = idx >> 12;
  int g = sg % 6;
  int s = sg / 6;
  int k = s * 16 + (l >> 5) * 8 + j;
  int n = c * 32 + (l & 31);
  const float* src = (g == 0) ? Wu : (g == 1) ? Wr : (g == 2) ? Wh
                   : (g == 3) ? Uu : (g == 4) ? Ur : Uh;
  wt[idx] = f2bf(src[k * 256 + n]);
}

// Persistent fused AUGRU. Grid = 256 blocks x 512 thr (8 waves); block b
// handles stripes b, b+256, b+512, b+768 (64 rows each). Same wave tile /
// W-ring / K-loop as the 92us kernel, but x/h tiles are DOUBLE-BUFFERED:
// next stripe's tiles are loaded+converted+written during this stripe's
// barrier-free K-passes (issue-early/write-late). One barrier per stripe.
__global__ __launch_bounds__(512, 2) void augru_main(
    const float* __restrict__ x, const float* __restrict__ h1,
    const float* __restrict__ a, const unsigned short* __restrict__ wt,
    const float* __restrict__ bu, const float* __restrict__ br,
    const float* __restrict__ bh, float* __restrict__ out) {
  extern __shared__ char smem[];   // [x0|x1|h0|h1] = 4 x 32 KB

  const int tid = threadIdx.x;
  const int l   = tid & 63;
  const int wid = tid >> 6;            // 0..7 -> 32-col chunk
  const int fr  = l & 31;
  const int fq  = l >> 5;
  const int n = wid * 32 + fr;
  const int aswz = (fr & 7) << 4;
  const char* wb = (const char*)wt + (wid << 10) + (l << 4);
#define WOFF(SG) ((long)(SG) << 13)

  const float vbu = bu[n], vbr = br[n], vbh = bh[n];

  // ---- W ring init: slabs 0..3, x-gates ----
  short8 W[4][3];
#pragma unroll
  for (int i = 0; i < 4; ++i)
#pragma unroll
    for (int g = 0; g < 3; ++g)
      W[i][g] = *(const short8*)(wb + WOFF(i * 6 + g));

#define TWRITE(DST, V, I)                                                   \
  {                                                                         \
    const int f_ = (I) * 512 + tid;                                         \
    const int row_ = f_ >> 6;                                               \
    const int kq_ = f_ & 63;                                                \
    ushort4 b_;                                                             \
    b_.x = f2bf((V).x); b_.y = f2bf((V).y);                                 \
    b_.z = f2bf((V).z); b_.w = f2bf((V).w);                                 \
    *(ushort4*)((DST) + (row_ << 9) + ((kq_ * 8) ^ ((row_ & 7) << 4))) = b_;\
  }

  // ---- stripe 0 prologue: stage x then h into buffer 0 ----
  long rowbase = (long)blockIdx.x * 64;
  char* pXc = smem;
  char* pXn = smem + 32768;
  char* pHc = smem + 65536;
  char* pHn = smem + 98304;

  float4 sv[8];
  {
    const float* xs = x + rowbase * 256;
#pragma unroll
    for (int i = 0; i < 8; ++i) sv[i] = ((const float4*)xs)[i * 512 + tid];
#pragma unroll
    for (int i = 0; i < 8; ++i) TWRITE(pXc, sv[i], i)
    const float* hs = h1 + rowbase * 256;
#pragma unroll
    for (int i = 0; i < 8; ++i) sv[i] = ((const float4*)hs)[i * 512 + tid];
#pragma unroll
    for (int i = 0; i < 8; ++i) TWRITE(pHc, sv[i], i)
  }
  __syncthreads();

  f32x16 accU0 = {}, accU1 = {}, accR0 = {}, accR1 = {};
  f32x16 accXH0 = {}, accXH1 = {}, accHH0 = {}, accHH1 = {};

  for (int it = 0; it < 4; ++it) {
    const long nrb = rowbase + 256 * 64;          // next stripe row base
    const float* nxs = x + nrb * 256;
    const float* nhs = h1 + nrb * 256;
    const bool more = (it < 3);

    // ---- x-pass: slabs 0..15, gates 0-2. No barriers. ----
#pragma unroll
    for (int p = 0; p < 16; ++p) {
      const int koff = ((p << 5) + (fq << 4)) ^ aswz;
      short8 a0 = *(const short8*)(pXc + (fr << 9) + koff);
      short8 a1 = *(const short8*)(pXc + ((fr + 32) << 9) + koff);
      accU0  = MFMA32(a0, W[p & 3][0], accU0, 0, 0, 0);
      accU1  = MFMA32(a1, W[p & 3][0], accU1, 0, 0, 0);
      accR0  = MFMA32(a0, W[p & 3][1], accR0, 0, 0, 0);
      accR1  = MFMA32(a1, W[p & 3][1], accR1, 0, 0, 0);
      accXH0 = MFMA32(a0, W[p & 3][2], accXH0, 0, 0, 0);
      accXH1 = MFMA32(a1, W[p & 3][2], accXH1, 0, 0, 0);
      {
        const long ro = (p + 4 < 16) ? WOFF((p + 4) * 6)
                                     : WOFF((p - 12) * 6 + 3);
        W[p & 3][0] = *(const short8*)(wb + ro);
        W[p & 3][1] = *(const short8*)(wb + ro + 8192);
        W[p & 3][2] = *(const short8*)(wb + ro + 16384);
      }
      if (p == 0 && more) {
#pragma unroll
        for (int i = 0; i < 8; ++i) sv[i] = ((const float4*)nxs)[i * 512 + tid];
      }
      if (p == 8 && more) {
        TWRITE(pXn, sv[0], 0) TWRITE(pXn, sv[1], 1)
        TWRITE(pXn, sv[2], 2) TWRITE(pXn, sv[3], 3)
        TWRITE(pXn, sv[4], 4) TWRITE(pXn, sv[5], 5)
        TWRITE(pXn, sv[6], 6) TWRITE(pXn, sv[7], 7)
      }
      if (p == 9 && more) {
#pragma unroll
        for (int i = 0; i < 8; ++i) sv[i] = ((const float4*)nhs)[i * 512 + tid];
      }
    }

    // ---- h-pass: slabs 0..15, gates 3-5. No barriers. ----
#pragma unroll
    for (int p = 0; p < 16; ++p) {
      const int koff = ((p << 5) + (fq << 4)) ^ aswz;
      short8 a0 = *(const short8*)(pHc + (fr << 9) + koff);
      short8 a1 = *(const short8*)(pHc + ((fr + 32) << 9) + koff);
      accU0  = MFMA32(a0, W[p & 3][0], accU0, 0, 0, 0);
      accU1  = MFMA32(a1, W[p & 3][0], accU1, 0, 0, 0);
      accR0  = MFMA32(a0, W[p & 3][1], accR0, 0, 0, 0);
      accR1  = MFMA32(a1, W[p & 3][1], accR1, 0, 0, 0);
      accHH0 = MFMA32(a0, W[p & 3][2], accHH0, 0, 0, 0);
      accHH1 = MFMA32(a1, W[p & 3][2], accHH1, 0, 0, 0);
      {
        // refill: h-gate slabs p+4, then next stripe's x-gate slabs 0..3
        const long ro = (p + 4 < 16) ? WOFF((p + 4) * 6 + 3)
                                     : WOFF((p - 12) * 6);
        W[p & 3][0] = *(const short8*)(wb + ro);
        W[p & 3][1] = *(const short8*)(wb + ro + 8192);
        W[p & 3][2] = *(const short8*)(wb + ro + 16384);
      }
      if (p == 4 && more) {
        TWRITE(pHn, sv[0], 0) TWRITE(pHn, sv[1], 1)
        TWRITE(pHn, sv[2], 2) TWRITE(pHn, sv[3], 3)
        TWRITE(pHn, sv[4], 4) TWRITE(pHn, sv[5], 5)
        TWRITE(pHn, sv[6], 6) TWRITE(pHn, sv[7], 7)
      }
    }

    // ---- epilogue: gates + blend for this stripe ----
    {
      const float* hcol = h1 + rowbase * 256 + n;
      const float* acol = a + rowbase;
      float* ocol = out + rowbase * 256 + n;
      float hE0[16], hE1[16];
#pragma unroll
      for (int g8 = 0; g8 < 4; ++g8)
#pragma unroll
        for (int j = 0; j < 4; ++j) {
          const int rl = g8 * 8 + fq * 4 + j;
          hE0[g8 * 4 + j] = hcol[(long)rl * 256];
          hE1[g8 * 4 + j] = hcol[(long)(rl + 32) * 256];
        }

#define EPI(ACCU, ACCR, ACCXH, ACCHH, HE, RB)                               \
  _Pragma("unroll")                                                         \
  for (int g8 = 0; g8 < 4; ++g8) {                                          \
    _Pragma("unroll")                                                       \
    for (int j = 0; j < 4; ++j) {                                           \
      const int reg = g8 * 4 + j;                                           \
      const int rl  = (RB) + g8 * 8 + fq * 4 + j;                           \
      const float pu = ACCU[reg] + vbu;                                     \
      const float pr = ACCR[reg] + vbr;                                     \
      const float uu = __builtin_amdgcn_rcpf(1.f + __expf(-pu));            \
      const float rr = __builtin_amdgcn_rcpf(1.f + __expf(-pr));            \
      const float cc = fmaf(rr, ACCHH[reg], ACCXH[reg]) + vbh;              \
      const float tt = __builtin_amdgcn_rcpf(1.f + __expf(-2.f * cc));      \
      const float th = fmaf(2.f, tt, -1.f);                                 \
      const float uh = acol[rl] * uu;                                       \
      const float h1v = HE[reg];                                            \
      ocol[(long)rl * 256] = fmaf(uh, th - h1v, h1v);                       \
    }                                                                       \
  }

      EPI(accU0, accR0, accXH0, accHH0, hE0, 0)
      EPI(accU1, accR1, accXH1, accHH1, hE1, 32)
#undef EPI
    }

    // ---- reset acc, swap buffers, advance ----
    {
      const f32x16 fz = {};
      accU0 = fz; accU1 = fz; accR0 = fz; accR1 = fz;
      accXH0 = fz; accXH1 = fz; accHH0 = fz; accHH1 = fz;
    }
    rowbase = nrb;
    { char* t = pXc; pXc = pXn; pXn = t; }
    { char* t = pHc; pHc = pHn; pHn = t; }
    __syncthreads();
  }
#undef TWRITE
#undef WOFF
}

extern "C" void kernel_launch(void* const* d_in, const int* in_sizes, int n_in,
                              void* d_out, int out_size, void* d_ws, size_t ws_size,
                              hipStream_t stream) {
  const float* x  = (const float*)d_in[0];
  const float* h1 = (const float*)d_in[1];
  const float* a  = (const float*)d_in[2];
  const float* Wu = (const float*)d_in[3];
  const float* Uu = (const float*)d_in[4];
  const float* bu = (const float*)d_in[5];
  const float* Wr = (const float*)d_in[6];
  const float* Ur = (const float*)d_in[7];
  const float* br = (const float*)d_in[8];
  const float* Wh = (const float*)d_in[9];
  const float* Uh = (const float*)d_in[10];
  const float* bh = (const float*)d_in[11];
  unsigned short* wt = (unsigned short*)d_ws;   // 16 slabs x 48 KB = 768 KB

  wprep<<<1536, 256, 0, stream>>>(Wu, Wr, Wh, Uu, Ur, Uh, wt);

  const int lds_bytes = 131072;                 // 2 x (32K x + 32K h)
  hipFuncSetAttribute((const void*)augru_main,
                      hipFuncAttributeMaxDynamicSharedMemorySize, lds_bytes);

  augru_main<<<256, 512, lds_bytes, stream>>>(x, h1, a, wt, bu, br, bh,
                                              (float*)d_out);
}